// Round 1
// baseline (260.246 us; speedup 1.0000x reference)
//
#include <hip/hip_runtime.h>
#include <stdint.h>

// Bahdanau additive attention, MI355X / gfx950.
// Inputs fp32, outputs fp32 (ctx[32*512] ++ aw[32*2048]).
// B=32, T=2048, D=512, U=512.  M = B*T = 65536.
//
// R9: resubmit of R8 unchanged — previous round's bench was an MI355X
//     container infra failure (no counters returned). Need baseline
//     counters (MfmaUtil / bank-conflict on attn_gemm, FETCH on context_k)
//     before the next structural edit.
// R8: B LDS layout XOR-swizzled (source-address permutation — global_load_lds
//     dest must stay lane-contiguous) to kill the 8-way ds_read bank conflict
//     found in R7 (SQ_LDS_BANK_CONFLICT=4.7M). Bank = 16*(lc&1)+4*(quad^swz)
//     -> 2-way = free.

typedef unsigned short ushort_t;
typedef __attribute__((ext_vector_type(8))) short short8;
typedef __attribute__((ext_vector_type(4))) float f32x4;
typedef __attribute__((ext_vector_type(2))) float float2v;
typedef __attribute__((ext_vector_type(2))) __bf16 bf162v;

#define GLOBAL_AS __attribute__((address_space(1)))
#define LDS_AS    __attribute__((address_space(3)))

__device__ __forceinline__ ushort_t f2bf(float f) {
    uint32_t u = __builtin_bit_cast(uint32_t, f);
    u = (u + 0x7fffu + ((u >> 16) & 1u)) >> 16;   // RNE
    return (ushort_t)u;
}
__device__ __forceinline__ uint32_t pkbf(float a, float b) {
    bf162v r = __builtin_convertvector((float2v){a, b}, bf162v);
    return __builtin_bit_cast(uint32_t, r);
}

// --------------------------- fused prep: uh GEMV + WkT transpose + ctx zero
// grid 576 = 256 uh | 256 WkT | 64 ctx-zero
__global__ __launch_bounds__(256) void prep_all(
    const float* __restrict__ hidden, const float* __restrict__ Uk,
    const float* __restrict__ Ub, const float* __restrict__ Wb,
    const float* __restrict__ Wk,
    float* __restrict__ uh, ushort_t* __restrict__ WkT,
    float* __restrict__ ctx_out)
{
    const int pb = blockIdx.x;
    if (pb < 256) {
        // uh[b][u] = hidden[b]·Uk[:,u] + Ub[u] + Wb[u]
        const int b  = pb >> 3;
        const int u  = (pb & 7) * 64 + (threadIdx.x & 63);
        const int k0 = (threadIdx.x >> 6) * 128;
        const float* hr = hidden + b * 512;
        float acc = 0.f;
        #pragma unroll 8
        for (int k = k0; k < k0 + 128; ++k)
            acc += hr[k] * Uk[k * 512 + u];
        __shared__ float red[256];
        red[threadIdx.x] = acc;
        __syncthreads();
        if (threadIdx.x < 64) {
            const int ul = threadIdx.x;
            uh[b * 512 + u] = red[ul] + red[ul + 64] + red[ul + 128] + red[ul + 192]
                            + Ub[u] + Wb[u];
        }
    } else if (pb < 512) {
        // WkT[u][d] = bf16(Wk[d][u]) via 32x32 LDS tile
        __shared__ float t[32][33];
        const int blk = pb - 256;
        const int ti = blk >> 4;
        const int tj = blk & 15;
        const int tx = threadIdx.x & 31;
        const int ty = threadIdx.x >> 5;
        #pragma unroll
        for (int q = 0; q < 4; ++q) {
            const int r = ty * 4 + q;
            t[r][tx] = Wk[(ti * 32 + r) * 512 + tj * 32 + tx];
        }
        __syncthreads();
        #pragma unroll
        for (int q = 0; q < 4; ++q) {
            const int r = ty * 4 + q;
            WkT[(tj * 32 + r) * 512 + ti * 32 + tx] = f2bf(t[tx][r]);
        }
    } else {
        ctx_out[(pb - 512) * 256 + threadIdx.x] = 0.f;   // zero ctx in d_out
    }
}

// ------------------------------------------------ fused GEMM+tanh+Vk-dot
// grid 512 M-tiles of 128 rows; 1024 threads = 16 waves (2M x 8N, 64x64 each).
// All N=512 held in acc. A fp32->bf16 in-kernel; B double-buffered + swizzled.
#define APAD 40   // A row stride in shorts (2-way banks = free)
__global__ __launch_bounds__(1024, 4) void attn_gemm(
    const float* __restrict__ feats, const ushort_t* __restrict__ WkT,
    const float* __restrict__ uh, const float* __restrict__ Vk,
    float* __restrict__ lg)
{
    __shared__ __align__(16) short As[2][128 * APAD];
    __shared__ __align__(16) short Bs[2][512 * 32];
    __shared__ float uh_s[512];
    __shared__ float vk_s[512];
    __shared__ float lpart[8][128];

    const int tid  = threadIdx.x;
    const int lane = tid & 63;
    const int quad = lane >> 4;
    const int lc   = lane & 15;
    const int wave = tid >> 6;       // 0..15
    const int wm   = wave >> 3;      // 0..1  (64-row strip)
    const int wn   = wave & 7;       // 0..7  (64-col strip)
    const int m0   = blockIdx.x * 128;
    const int bidx = m0 >> 11;       // batch index (uniform per block)

    if (tid < 512) {
        uh_s[tid] = uh[bidx * 512 + tid];
        vk_s[tid] = Vk[tid];
    }

    const int rowA = tid >> 3;          // 0..127
    const int kAo  = (tid & 7) * 4;     // fp32 k-offset 0..28
    // B staging swizzle: lds slot s of row r holds global k-slot s ^ ((r>>1)&3)
    const int rB0  = tid >> 2;          // rnd 0 row (0..255)
    const int sB   = tid & 3;           // lds k-slot

    f32x4 acc[4][4];
    #pragma unroll
    for (int tm = 0; tm < 4; ++tm)
        #pragma unroll
        for (int tn = 0; tn < 4; ++tn)
            acc[tm][tn] = (f32x4){0.f, 0.f, 0.f, 0.f};

    // ---- prologue: stage chunk 0 into buf 0
    {
        #pragma unroll
        for (int rnd = 0; rnd < 2; ++rnd) {
            const int li = rnd * 1024 + tid;
            const int rB = rnd * 256 + rB0;
            const int kq = (sB ^ ((rB >> 1) & 3)) * 8;
            const ushort_t* gb = WkT + (size_t)rB * 512 + kq;
            __builtin_amdgcn_global_load_lds(
                (const GLOBAL_AS void*)gb, (LDS_AS void*)(Bs[0] + li * 8), 16, 0, 0);
        }
        const f32x4 av = *(const f32x4*)(feats + (size_t)(m0 + rowA) * 512 + kAo);
        uint2 w;
        w.x = pkbf(av.x, av.y);
        w.y = pkbf(av.z, av.w);
        *(uint2*)(As[0] + rowA * APAD + kAo) = w;
    }

    const int swzR = (lc >> 1) & 3;     // fragment-read swizzle (row = ...+lc)

    int buf = 0;
    for (int ks = 0; ks < 16; ++ks) {   // K = 512, BK = 32
        __syncthreads();                // staging of `buf` complete

        f32x4 a_next;
        const bool have = (ks + 1) < 16;
        if (have) {
            const int k0n = (ks + 1) * 32;
            #pragma unroll
            for (int rnd = 0; rnd < 2; ++rnd) {
                const int li = rnd * 1024 + tid;
                const int rB = rnd * 256 + rB0;
                const int kq = (sB ^ ((rB >> 1) & 3)) * 8;
                const ushort_t* gb = WkT + (size_t)rB * 512 + k0n + kq;
                __builtin_amdgcn_global_load_lds(
                    (const GLOBAL_AS void*)gb, (LDS_AS void*)(Bs[buf ^ 1] + li * 8),
                    16, 0, 0);
            }
            a_next = *(const f32x4*)(feats + (size_t)(m0 + rowA) * 512 + k0n + kAo);
        }

        // ---- compute on `buf` (hides the loads above)
        short8 af[4], bfr[4];
        #pragma unroll
        for (int t4 = 0; t4 < 4; ++t4) {
            af[t4]  = *(const short8*)(As[buf] + (wm * 64 + t4 * 16 + lc) * APAD + quad * 8);
            bfr[t4] = *(const short8*)(Bs[buf] + (wn * 64 + t4 * 16 + lc) * 32
                                       + ((quad ^ swzR) * 8));
        }
        #pragma unroll
        for (int tm = 0; tm < 4; ++tm)
            #pragma unroll
            for (int tn = 0; tn < 4; ++tn)
                acc[tm][tn] = __builtin_amdgcn_mfma_f32_16x16x32_bf16(
                    af[tm], bfr[tn], acc[tm][tn], 0, 0, 0);

        if (have) {
            uint2 w;
            w.x = pkbf(a_next.x, a_next.y);
            w.y = pkbf(a_next.z, a_next.w);
            *(uint2*)(As[buf ^ 1] + rowA * APAD + kAo) = w;
        }
        buf ^= 1;
    }

    // epilogue: tanh(acc + uh) * Vk -> per-row partials
    // C/D layout: col = lane&15, row = quad*4 + reg   [m89-verified]
    float rp[16];
    #pragma unroll
    for (int i = 0; i < 16; ++i) rp[i] = 0.f;
    #pragma unroll
    for (int tn = 0; tn < 4; ++tn) {
        const int nl  = wn * 64 + tn * 16 + lc;
        const float uhv = uh_s[nl];
        const float vkv = vk_s[nl];
        #pragma unroll
        for (int tm = 0; tm < 4; ++tm)
            #pragma unroll
            for (int i = 0; i < 4; ++i) {
                const float x = acc[tm][tn][i] + uhv;
                const float e = __expf(2.0f * x);          // tanh = 1 - 2/(e^{2x}+1)
                rp[tm * 4 + i] += (1.0f - 2.0f / (e + 1.0f)) * vkv;
            }
    }
    #pragma unroll
    for (int i = 0; i < 16; ++i) {
        float v = rp[i];
        v += __shfl_xor(v, 1, 64);
        v += __shfl_xor(v, 2, 64);
        v += __shfl_xor(v, 4, 64);
        v += __shfl_xor(v, 8, 64);
        rp[i] = v;
    }
    if (lc == 0) {
        #pragma unroll
        for (int tm = 0; tm < 4; ++tm)
            #pragma unroll
            for (int i = 0; i < 4; ++i)
                lpart[wn][wm * 64 + tm * 16 + quad * 4 + i] = rp[tm * 4 + i];
    }
    __syncthreads();
    if (tid < 128) {
        float s = 0.f;
        #pragma unroll
        for (int j = 0; j < 8; ++j) s += lpart[j][tid];
        lg[m0 + tid] = s;
    }
}

// ---------------------------------------------------------------- softmax
__global__ __launch_bounds__(256) void softmax_k(
    const float* __restrict__ lg, float* __restrict__ aw_out)
{
    const int b = blockIdx.x, tid = threadIdx.x;
    const float* p = lg + b * 2048;
    float v[8];
    #pragma unroll
    for (int i = 0; i < 8; ++i) v[i] = p[tid + i * 256];
    float mx = -1e30f;
    #pragma unroll
    for (int i = 0; i < 8; ++i) mx = fmaxf(mx, v[i]);
    #pragma unroll
    for (int off = 32; off >= 1; off >>= 1) mx = fmaxf(mx, __shfl_xor(mx, off, 64));
    __shared__ float redm[4], reds[4];
    const int wv = tid >> 6, ln = tid & 63;
    if (ln == 0) redm[wv] = mx;
    __syncthreads();
    mx = fmaxf(fmaxf(redm[0], redm[1]), fmaxf(redm[2], redm[3]));
    float s = 0.f;
    #pragma unroll
    for (int i = 0; i < 8; ++i) { v[i] = __expf(v[i] - mx); s += v[i]; }
    #pragma unroll
    for (int off = 32; off >= 1; off >>= 1) s += __shfl_xor(s, off, 64);
    if (ln == 0) reds[wv] = s;
    __syncthreads();
    s = reds[0] + reds[1] + reds[2] + reds[3];
    const float inv = 1.0f / s;
    #pragma unroll
    for (int i = 0; i < 8; ++i)
        aw_out[b * 2048 + tid + i * 256] = v[i] * inv;
}

// ------------------------------------------------------- context reduction
// grid 512 = 32 b x 16 t-chunks(128); thread: float4 over d, 64 t's.
__global__ __launch_bounds__(256) void context_k(
    const float* __restrict__ feats, const float* __restrict__ aw,
    float* __restrict__ ctx_out)
{
    const int b  = blockIdx.x >> 4;
    const int t0 = (blockIdx.x & 15) * 128 + (threadIdx.x >> 7) * 64;
    const int d4 = (threadIdx.x & 127) * 4;
    const float* wp = aw + b * 2048 + t0;
    const float* fp = feats + (size_t)(b * 2048 + t0) * 512 + d4;
    f32x4 a = (f32x4){0.f, 0.f, 0.f, 0.f};
    #pragma unroll 4
    for (int tt = 0; tt < 64; ++tt) {
        const float w = wp[tt];
        const f32x4 f = *(const f32x4*)(fp + (size_t)tt * 512);
        a.x += w * f.x; a.y += w * f.y; a.z += w * f.z; a.w += w * f.w;
    }
    atomicAdd(&ctx_out[b * 512 + d4],     a.x);
    atomicAdd(&ctx_out[b * 512 + d4 + 1], a.y);
    atomicAdd(&ctx_out[b * 512 + d4 + 2], a.z);
    atomicAdd(&ctx_out[b * 512 + d4 + 3], a.w);
}

// ---------------------------------------------------------------- launch
extern "C" void kernel_launch(void* const* d_in, const int* in_sizes, int n_in,
                              void* d_out, int out_size, void* d_ws, size_t ws_size,
                              hipStream_t stream)
{
    const float* feats  = (const float*)d_in[0];
    const float* hidden = (const float*)d_in[1];
    const float* Wk     = (const float*)d_in[2];
    const float* Wb     = (const float*)d_in[3];
    const float* Uk     = (const float*)d_in[4];
    const float* Ub     = (const float*)d_in[5];
    const float* Vk     = (const float*)d_in[6];
    // d_in[7] = Vb: constant logit shift, cancels in softmax.

    float* out       = (float*)d_out;
    float* ctx_out_p = out;               // [32*512]  fp32 (atomic target)
    float* aw_out_p  = out + 16384;       // [32*2048] fp32

    char* ws = (char*)d_ws;
    float*    uh  = (float*)ws;                      // 64 KB
    ushort_t* WkT = (ushort_t*)(ws + 65536);         // 512 KB
    float*    lg  = (float*)(ws + 589824);           // 256 KB

    prep_all <<<576, 256, 0, stream>>>(hidden, Uk, Ub, Wb, Wk, uh, WkT, ctx_out_p);
    attn_gemm<<<512, 1024, 0, stream>>>(feats, WkT, uh, Vk, lg);
    softmax_k<<<32,  256, 0, stream>>>(lg, aw_out_p);
    context_k<<<512, 256, 0, stream>>>(feats, aw_out_p, ctx_out_p);
}

// Round 2
// 255.885 us; speedup vs baseline: 1.0170x; 1.0170x over previous
//
#include <hip/hip_runtime.h>
#include <stdint.h>

// Bahdanau additive attention, MI355X / gfx950.
// Inputs fp32, outputs fp32 (ctx[32*512] ++ aw[32*2048]).
// B=32, T=2048, D=512, U=512.  M = B*T = 65536.
//
// R10: context_k atomics removed. Old path: 524K device-scope fp32 atomicAdds
//      into 64KB, 32 writers/address -> same-address serialization + cross-XCD
//      line ping-pong (theory for the ~120us hidden behind attn_gemm's 76us).
//      New path: context_part writes disjoint per-(chunk,half) partials to ws
//      (no atomics, coalesced), context_reduce sums 32 partials/output.
//      prep_all ctx-zero branch dropped (grid 576->512). attn_gemm untouched.
// R8/R9: B LDS layout XOR-swizzled; baseline counters captured.

typedef unsigned short ushort_t;
typedef __attribute__((ext_vector_type(8))) short short8;
typedef __attribute__((ext_vector_type(4))) float f32x4;
typedef __attribute__((ext_vector_type(2))) float float2v;
typedef __attribute__((ext_vector_type(2))) __bf16 bf162v;

#define GLOBAL_AS __attribute__((address_space(1)))
#define LDS_AS    __attribute__((address_space(3)))

__device__ __forceinline__ ushort_t f2bf(float f) {
    uint32_t u = __builtin_bit_cast(uint32_t, f);
    u = (u + 0x7fffu + ((u >> 16) & 1u)) >> 16;   // RNE
    return (ushort_t)u;
}
__device__ __forceinline__ uint32_t pkbf(float a, float b) {
    bf162v r = __builtin_convertvector((float2v){a, b}, bf162v);
    return __builtin_bit_cast(uint32_t, r);
}

// --------------------------- fused prep: uh GEMV + WkT transpose
// grid 512 = 256 uh | 256 WkT
__global__ __launch_bounds__(256) void prep_all(
    const float* __restrict__ hidden, const float* __restrict__ Uk,
    const float* __restrict__ Ub, const float* __restrict__ Wb,
    const float* __restrict__ Wk,
    float* __restrict__ uh, ushort_t* __restrict__ WkT)
{
    const int pb = blockIdx.x;
    if (pb < 256) {
        // uh[b][u] = hidden[b]·Uk[:,u] + Ub[u] + Wb[u]
        const int b  = pb >> 3;
        const int u  = (pb & 7) * 64 + (threadIdx.x & 63);
        const int k0 = (threadIdx.x >> 6) * 128;
        const float* hr = hidden + b * 512;
        float acc = 0.f;
        #pragma unroll 8
        for (int k = k0; k < k0 + 128; ++k)
            acc += hr[k] * Uk[k * 512 + u];
        __shared__ float red[256];
        red[threadIdx.x] = acc;
        __syncthreads();
        if (threadIdx.x < 64) {
            const int ul = threadIdx.x;
            uh[b * 512 + u] = red[ul] + red[ul + 64] + red[ul + 128] + red[ul + 192]
                            + Ub[u] + Wb[u];
        }
    } else {
        // WkT[u][d] = bf16(Wk[d][u]) via 32x32 LDS tile
        __shared__ float t[32][33];
        const int blk = pb - 256;
        const int ti = blk >> 4;
        const int tj = blk & 15;
        const int tx = threadIdx.x & 31;
        const int ty = threadIdx.x >> 5;
        #pragma unroll
        for (int q = 0; q < 4; ++q) {
            const int r = ty * 4 + q;
            t[r][tx] = Wk[(ti * 32 + r) * 512 + tj * 32 + tx];
        }
        __syncthreads();
        #pragma unroll
        for (int q = 0; q < 4; ++q) {
            const int r = ty * 4 + q;
            WkT[(tj * 32 + r) * 512 + ti * 32 + tx] = f2bf(t[tx][r]);
        }
    }
}

// ------------------------------------------------ fused GEMM+tanh+Vk-dot
// grid 512 M-tiles of 128 rows; 1024 threads = 16 waves (2M x 8N, 64x64 each).
// All N=512 held in acc. A fp32->bf16 in-kernel; B double-buffered + swizzled.
#define APAD 40   // A row stride in shorts (2-way banks = free)
__global__ __launch_bounds__(1024, 4) void attn_gemm(
    const float* __restrict__ feats, const ushort_t* __restrict__ WkT,
    const float* __restrict__ uh, const float* __restrict__ Vk,
    float* __restrict__ lg)
{
    __shared__ __align__(16) short As[2][128 * APAD];
    __shared__ __align__(16) short Bs[2][512 * 32];
    __shared__ float uh_s[512];
    __shared__ float vk_s[512];
    __shared__ float lpart[8][128];

    const int tid  = threadIdx.x;
    const int lane = tid & 63;
    const int quad = lane >> 4;
    const int lc   = lane & 15;
    const int wave = tid >> 6;       // 0..15
    const int wm   = wave >> 3;      // 0..1  (64-row strip)
    const int wn   = wave & 7;       // 0..7  (64-col strip)
    const int m0   = blockIdx.x * 128;
    const int bidx = m0 >> 11;       // batch index (uniform per block)

    if (tid < 512) {
        uh_s[tid] = uh[bidx * 512 + tid];
        vk_s[tid] = Vk[tid];
    }

    const int rowA = tid >> 3;          // 0..127
    const int kAo  = (tid & 7) * 4;     // fp32 k-offset 0..28
    // B staging swizzle: lds slot s of row r holds global k-slot s ^ ((r>>1)&3)
    const int rB0  = tid >> 2;          // rnd 0 row (0..255)
    const int sB   = tid & 3;           // lds k-slot

    f32x4 acc[4][4];
    #pragma unroll
    for (int tm = 0; tm < 4; ++tm)
        #pragma unroll
        for (int tn = 0; tn < 4; ++tn)
            acc[tm][tn] = (f32x4){0.f, 0.f, 0.f, 0.f};

    // ---- prologue: stage chunk 0 into buf 0
    {
        #pragma unroll
        for (int rnd = 0; rnd < 2; ++rnd) {
            const int li = rnd * 1024 + tid;
            const int rB = rnd * 256 + rB0;
            const int kq = (sB ^ ((rB >> 1) & 3)) * 8;
            const ushort_t* gb = WkT + (size_t)rB * 512 + kq;
            __builtin_amdgcn_global_load_lds(
                (const GLOBAL_AS void*)gb, (LDS_AS void*)(Bs[0] + li * 8), 16, 0, 0);
        }
        const f32x4 av = *(const f32x4*)(feats + (size_t)(m0 + rowA) * 512 + kAo);
        uint2 w;
        w.x = pkbf(av.x, av.y);
        w.y = pkbf(av.z, av.w);
        *(uint2*)(As[0] + rowA * APAD + kAo) = w;
    }

    const int swzR = (lc >> 1) & 3;     // fragment-read swizzle (row = ...+lc)

    int buf = 0;
    for (int ks = 0; ks < 16; ++ks) {   // K = 512, BK = 32
        __syncthreads();                // staging of `buf` complete

        f32x4 a_next;
        const bool have = (ks + 1) < 16;
        if (have) {
            const int k0n = (ks + 1) * 32;
            #pragma unroll
            for (int rnd = 0; rnd < 2; ++rnd) {
                const int li = rnd * 1024 + tid;
                const int rB = rnd * 256 + rB0;
                const int kq = (sB ^ ((rB >> 1) & 3)) * 8;
                const ushort_t* gb = WkT + (size_t)rB * 512 + k0n + kq;
                __builtin_amdgcn_global_load_lds(
                    (const GLOBAL_AS void*)gb, (LDS_AS void*)(Bs[buf ^ 1] + li * 8),
                    16, 0, 0);
            }
            a_next = *(const f32x4*)(feats + (size_t)(m0 + rowA) * 512 + k0n + kAo);
        }

        // ---- compute on `buf` (hides the loads above)
        short8 af[4], bfr[4];
        #pragma unroll
        for (int t4 = 0; t4 < 4; ++t4) {
            af[t4]  = *(const short8*)(As[buf] + (wm * 64 + t4 * 16 + lc) * APAD + quad * 8);
            bfr[t4] = *(const short8*)(Bs[buf] + (wn * 64 + t4 * 16 + lc) * 32
                                       + ((quad ^ swzR) * 8));
        }
        #pragma unroll
        for (int tm = 0; tm < 4; ++tm)
            #pragma unroll
            for (int tn = 0; tn < 4; ++tn)
                acc[tm][tn] = __builtin_amdgcn_mfma_f32_16x16x32_bf16(
                    af[tm], bfr[tn], acc[tm][tn], 0, 0, 0);

        if (have) {
            uint2 w;
            w.x = pkbf(a_next.x, a_next.y);
            w.y = pkbf(a_next.z, a_next.w);
            *(uint2*)(As[buf ^ 1] + rowA * APAD + kAo) = w;
        }
        buf ^= 1;
    }

    // epilogue: tanh(acc + uh) * Vk -> per-row partials
    // C/D layout: col = lane&15, row = quad*4 + reg   [m89-verified]
    float rp[16];
    #pragma unroll
    for (int i = 0; i < 16; ++i) rp[i] = 0.f;
    #pragma unroll
    for (int tn = 0; tn < 4; ++tn) {
        const int nl  = wn * 64 + tn * 16 + lc;
        const float uhv = uh_s[nl];
        const float vkv = vk_s[nl];
        #pragma unroll
        for (int tm = 0; tm < 4; ++tm)
            #pragma unroll
            for (int i = 0; i < 4; ++i) {
                const float x = acc[tm][tn][i] + uhv;
                const float e = __expf(2.0f * x);          // tanh = 1 - 2/(e^{2x}+1)
                rp[tm * 4 + i] += (1.0f - 2.0f / (e + 1.0f)) * vkv;
            }
    }
    #pragma unroll
    for (int i = 0; i < 16; ++i) {
        float v = rp[i];
        v += __shfl_xor(v, 1, 64);
        v += __shfl_xor(v, 2, 64);
        v += __shfl_xor(v, 4, 64);
        v += __shfl_xor(v, 8, 64);
        rp[i] = v;
    }
    if (lc == 0) {
        #pragma unroll
        for (int tm = 0; tm < 4; ++tm)
            #pragma unroll
            for (int i = 0; i < 4; ++i)
                lpart[wn][wm * 64 + tm * 16 + quad * 4 + i] = rp[tm * 4 + i];
    }
    __syncthreads();
    if (tid < 128) {
        float s = 0.f;
        #pragma unroll
        for (int j = 0; j < 8; ++j) s += lpart[j][tid];
        lg[m0 + tid] = s;
    }
}

// ---------------------------------------------------------------- softmax
__global__ __launch_bounds__(256) void softmax_k(
    const float* __restrict__ lg, float* __restrict__ aw_out)
{
    const int b = blockIdx.x, tid = threadIdx.x;
    const float* p = lg + b * 2048;
    float v[8];
    #pragma unroll
    for (int i = 0; i < 8; ++i) v[i] = p[tid + i * 256];
    float mx = -1e30f;
    #pragma unroll
    for (int i = 0; i < 8; ++i) mx = fmaxf(mx, v[i]);
    #pragma unroll
    for (int off = 32; off >= 1; off >>= 1) mx = fmaxf(mx, __shfl_xor(mx, off, 64));
    __shared__ float redm[4], reds[4];
    const int wv = tid >> 6, ln = tid & 63;
    if (ln == 0) redm[wv] = mx;
    __syncthreads();
    mx = fmaxf(fmaxf(redm[0], redm[1]), fmaxf(redm[2], redm[3]));
    float s = 0.f;
    #pragma unroll
    for (int i = 0; i < 8; ++i) { v[i] = __expf(v[i] - mx); s += v[i]; }
    #pragma unroll
    for (int off = 32; off >= 1; off >>= 1) s += __shfl_xor(s, off, 64);
    if (ln == 0) reds[wv] = s;
    __syncthreads();
    s = reds[0] + reds[1] + reds[2] + reds[3];
    const float inv = 1.0f / s;
    #pragma unroll
    for (int i = 0; i < 8; ++i)
        aw_out[b * 2048 + tid + i * 256] = v[i] * inv;
}

// ------------------------------------------------------- context, stage 1
// grid 512 = 32 b x 16 t-chunks(128); two 64-t halves per block write
// DISJOINT partial slots (no atomics). part[b][chunk*2+half][d].
__global__ __launch_bounds__(256) void context_part(
    const float* __restrict__ feats, const float* __restrict__ aw,
    float* __restrict__ part)
{
    const int b     = blockIdx.x >> 4;
    const int chunk = blockIdx.x & 15;
    const int half  = threadIdx.x >> 7;
    const int t0    = chunk * 128 + half * 64;
    const int d4    = (threadIdx.x & 127) * 4;
    const float* wp = aw + b * 2048 + t0;
    const float* fp = feats + (size_t)(b * 2048 + t0) * 512 + d4;
    f32x4 a = (f32x4){0.f, 0.f, 0.f, 0.f};
    #pragma unroll 4
    for (int tt = 0; tt < 64; ++tt) {
        const float w = wp[tt];
        const f32x4 f = *(const f32x4*)(fp + (size_t)tt * 512);
        a.x += w * f.x; a.y += w * f.y; a.z += w * f.z; a.w += w * f.w;
    }
    *(f32x4*)(part + (size_t)(b * 32 + chunk * 2 + half) * 512 + d4) = a;
}

// ------------------------------------------------------- context, stage 2
// grid 32 (b) x 512 threads (d): ctx[b][d] = sum_j part[b][j][d], j<32.
__global__ __launch_bounds__(512) void context_reduce(
    const float* __restrict__ part, float* __restrict__ ctx)
{
    const int b = blockIdx.x;
    const int d = threadIdx.x;
    const float* p = part + (size_t)b * 32 * 512 + d;
    float s = 0.f;
    #pragma unroll
    for (int j = 0; j < 32; ++j) s += p[j * 512];
    ctx[b * 512 + d] = s;
}

// ---------------------------------------------------------------- launch
extern "C" void kernel_launch(void* const* d_in, const int* in_sizes, int n_in,
                              void* d_out, int out_size, void* d_ws, size_t ws_size,
                              hipStream_t stream)
{
    const float* feats  = (const float*)d_in[0];
    const float* hidden = (const float*)d_in[1];
    const float* Wk     = (const float*)d_in[2];
    const float* Wb     = (const float*)d_in[3];
    const float* Uk     = (const float*)d_in[4];
    const float* Ub     = (const float*)d_in[5];
    const float* Vk     = (const float*)d_in[6];
    // d_in[7] = Vb: constant logit shift, cancels in softmax.

    float* out       = (float*)d_out;
    float* ctx_out_p = out;               // [32*512]  fp32
    float* aw_out_p  = out + 16384;       // [32*2048] fp32

    char* ws = (char*)d_ws;
    float*    uh   = (float*)ws;                      // 64 KB
    ushort_t* WkT  = (ushort_t*)(ws + 65536);         // 512 KB
    float*    lg   = (float*)(ws + 589824);           // 256 KB
    float*    part = (float*)(ws + 851968);           // 2 MB  (32*32*512 f32)

    prep_all      <<<512, 256, 0, stream>>>(hidden, Uk, Ub, Wb, Wk, uh, WkT);
    attn_gemm     <<<512, 1024, 0, stream>>>(feats, WkT, uh, Vk, lg);
    softmax_k     <<<32,  256, 0, stream>>>(lg, aw_out_p);
    context_part  <<<512, 256, 0, stream>>>(feats, aw_out_p, part);
    context_reduce<<<32,  512, 0, stream>>>(part, ctx_out_p);
}